// Round 10
// baseline (176.637 us; speedup 1.0000x reference)
//
#include <hip/hip_runtime.h>
#include <hip/hip_bf16.h>

// ---------------------------------------------------------------------------
// InferCellV2 R15: source-major DAG re-association, flat bf16 edge partials.
// R14 failed (uncoalesced fp32 gather in fused staging, +12us) -> reverted.
// Evidence synthesis: conv core at fragment-traffic floor (R12/R13b); the
// 148-154 plateau across different structures + R9's equal times for 1/2/3
// sources point at per-kernel FIXED costs: serial staging stalls (startup +
// mid-kernel source switches, uncovered at 1 block/CU). R12 pays 6 staging
// events. R15 reorganizes by SOURCE: K1 = r0-edges {E0->node1, E1->p2,
// E3->p3}; K2 = node1-edges {E2->node2(+p2), E4->p3}; K3 = {E5->out(+p3)}.
// Partials p2/p3 = flat bf16 thread-owned 128B records (coalesced both ways;
// acc-init overlaps the staging wait; +2 bf16 roundings ~0.3 abs << tol).
// Each kernel stages A ONCE (3 mid-kernel A-restages gone; +1 cheap B-only
// restage in K1). Paired edges share each A-fragment: second edge's B comes
// from REGISTERS via the R13b frag-major wtR path (correctness-verified in
// R13b). LDS-read units 48 -> 40 (-17%), no new barriers. Reg peak in paired
// phase: 128 acc + 16 Af + 16 Bf + 32 Bb ~ 222 < 256 (single-buffered frags
// there; R12's verified fA/fB[2][4] pipeline kept in single-edge phases).
// Verified pieces kept byte-identical: A layout/staging/swizzle, LDS-B
// layout+ldB, oc-permute (acc col n*16+l15 = true oc l15*4+n), node/f32
// epilogues, pre_kernel, __launch_bounds__(512,1), grid 256 = 1 block/CU.
// ---------------------------------------------------------------------------

typedef __bf16 bf16x8 __attribute__((ext_vector_type(8)));
typedef float floatx4 __attribute__((ext_vector_type(4)));
typedef unsigned int uint32;
typedef uint32 u32x4 __attribute__((ext_vector_type(4)));

#define PADW 34
#define PIMG (PADW * PADW)
#define ROWB (PADW * 64 * 2)        // 4352 B per padded NHWC row
#define A_LDS (18 * ROWB)           // 78336 (16 out rows + 2 halo)
#define A_CHUNKS (A_LDS / 16)       // 4896 = 9*512 + 288
#define A_TAIL (A_CHUNKS - 9 * 512) // 288
#define TAPB (64 * 64 * 2)          // 8192 B per weight tap
#define B_LDS (9 * TAPB)            // 73728
#define SMEM_BYTES (A_LDS + B_LDS)  // 152064 -> 1 block/CU

__device__ __forceinline__ void gld16(const char* g, char* l) {
    __builtin_amdgcn_global_load_lds(
        (const __attribute__((address_space(1))) uint32*)g,
        (__attribute__((address_space(3))) uint32*)l, 16, 0, 0);
}

// ---------------- fused pre-pass: weights (2 layouts) + halo + relu_pad -----
__global__ __launch_bounds__(256) void pre_kernel(
    const float* __restrict__ in, const float* __restrict__ a1,
    const float* __restrict__ a2, const float* __restrict__ W,
    __hip_bfloat16* __restrict__ wt, __hip_bfloat16* __restrict__ wtR,
    __hip_bfloat16* __restrict__ r0, __hip_bfloat16* __restrict__ r1,
    __hip_bfloat16* __restrict__ r2) {
    __shared__ float tile[32][65];
    int blk = blockIdx.x;
    int tid = threadIdx.x;

    if (blk < 864) {                 // ---- weights: scale + both layouts
        int idx = blk * 256 + tid;   // 6*9*64*64 = 221184 exact
        int i = idx & 63;
        int o = (idx >> 6) & 63;     // TRUE oc
        int rest = idx >> 12;
        int t = rest % 9;
        int l = rest / 9;
        int ji = i >> 3, jo = o >> 3;
        float ain = 0.f, aout = 0.f;
#pragma unroll
        for (int j = 0; j < 8; ++j) {
            ain  += (j >= ji) ? a1[j] : 0.f;
            aout += (j >= jo) ? a2[j] : 0.f;
        }
        float v = W[(size_t)((l * 64 + o) * 64 + i) * 9 + t] * ain * aout;
        int os = ((o & 3) << 4) + (o >> 2);      // oc-permute storage col
        // layout 1 (LDS gld16 path, verified R11/R12):
        size_t e = (size_t)(l * 9 + t) * 4096 + os * 64 +
                   ((((i >> 3) ^ (os & 7)) << 3) + (i & 7));
        __hip_bfloat16 bv = __float2bfloat16(v);
        wt[e] = bv;
        // layout 2 (frag-major reg path, verified R13b):
        int n  = os >> 4, c15 = os & 15;
        int q  = i >> 5, quad = (i >> 3) & 3, ee = i & 7;
        int ln = (quad << 4) + c15;
        size_t e2 = (size_t)(l * 9 + t) * 4096 + (((q << 2) + n) << 9) +
                    (ln << 3) + ee;
        wtR[e2] = bv;
    } else if (blk < 992) {          // ---- zero halo ring, image b
        int b = blk - 864;
        __hip_bfloat16* bufs[3] = {r0, r1, r2};
#pragma unroll
        for (int f = 0; f < 3; ++f) {
            uint32* buf = (uint32*)(bufs[f] + (size_t)b * PIMG * 64);
            for (int idx = tid; idx < 132 * 32; idx += 256) {
                int slot = idx >> 5, u = idx & 31;
                int yy, xx;
                if (slot < 34)      { yy = 0;  xx = slot; }
                else if (slot < 68) { yy = 33; xx = slot - 34; }
                else { int s2 = slot - 68; yy = 1 + (s2 >> 1); xx = (s2 & 1) * 33; }
                buf[(size_t)(yy * PADW + xx) * 32 + u] = 0u;
            }
        }
    } else {                         // ---- relu(x) -> padded swizzled NHWC
        int rb = blk - 992;
        int b = rb >> 5, y = rb & 31;
        int x = tid & 31, c0 = tid >> 5;
        const float* ip = in + ((size_t)b * 64 * 32 + y) * 32 + x;
#pragma unroll
        for (int cc = 0; cc < 8; ++cc) {
            int c = cc * 8 + c0;
            tile[x][c] = fmaxf(ip[(size_t)c * 1024], 0.f);
        }
        __syncthreads();
        int j = tid & 7, xq = tid >> 3;
        int p = (b * PADW + y + 1) * PADW + 1 + xq;
        alignas(16) __hip_bfloat16 hv[8];
#pragma unroll
        for (int k = 0; k < 8; ++k)
            hv[k] = __float2bfloat16(tile[xq][j * 8 + k]);
        *(uint4*)((char*)r0 + (size_t)p * 128 + ((j ^ (p & 7)) << 4)) =
            *(const uint4*)hv;
    }
}

#define ZERO4(A_)                                                        \
    _Pragma("unroll") for (int m_ = 0; m_ < 4; ++m_)                     \
    _Pragma("unroll") for (int n_ = 0; n_ < 4; ++n_)                     \
        A_[m_][n_] = (floatx4){0.f, 0.f, 0.f, 0.f};

// ---------------- source-major conv kernels --------------------------------
// Geometry (all modes identical): block: image b = blk>>1, strip
// y0 = (blk&1)*16; wave wv: rows y0+2wv,+1. A-frag: l15 = px,
// quad*8+q*32 = in-ch. LDS-B frag: l15 = storage col (true oc = l15*4+n).
// C/D: M(pixel) = quad*4+r. Partial records: thread-owned 128B at
// (blk*512+tid)*128, j = c*8+k -> (m,n,r) = (j>>4, (j>>2)&3, j&3).
// MODE 1: E0(LDS-B,l0)+E1(reg-B,l1) shared-A -> node1,p2; then E3(l3) -> p3.
// MODE 2: init p2,p3; E2(LDS-B,l2)+E4(reg-B,l4) shared-A -> node2,p3.
// MODE 3: init p3; E5(LDS-B,l5) pipelined -> fp32 out.
template <int MODE>
__global__ __launch_bounds__(512, 1) void conv_k(
    const __hip_bfloat16* __restrict__ Asrc,
    const __hip_bfloat16* __restrict__ wt,
    const __hip_bfloat16* __restrict__ wtR,
    __hip_bfloat16* __restrict__ nodeOut, float* __restrict__ finalOut,
    __hip_bfloat16* __restrict__ p2, __hip_bfloat16* __restrict__ p3) {
    extern __shared__ char smem[];               // A_LDS + B_LDS
    char* smemB = smem + A_LDS;
    int tid = threadIdx.x;
    int wv = tid >> 6, lane = tid & 63;
    int quad = lane >> 4, l15 = lane & 15;
    int blk = blockIdx.x;
    int b = blk >> 1, y0 = (blk & 1) << 4;
    const size_t aOff = (size_t)(b * PADW + y0) * PADW * 128;
    const size_t pbase = ((size_t)blk * 512 + tid) << 7;   // 128B record

    auto stage_A = [&]() {           // 18 padded rows, linear 16B DMA copy
        const char* gA = (const char*)Asrc + aOff;
#pragma unroll
        for (int it = 0; it < 10; ++it) {
            int c = it * 512 + tid;
            if (it < 9 || tid < A_TAIL)
                gld16(gA + (size_t)c * 16, smem + (it * 512 + wv * 64) * 16);
        }
    };
    auto stage_B = [&](int l) {      // 9 taps of edge l, linear 16B DMA copy
        const char* gB = (const char*)wt + (size_t)l * 9 * TAPB;
#pragma unroll
        for (int it = 0; it < 9; ++it) {
            int c = it * 512 + tid;
            gld16(gB + (size_t)c * 16, smemB + (it * 512 + wv * 64) * 16);
        }
    };
    auto ldA = [&](int tl, int q, bf16x8 (&dst)[4]) {
        const int ky = tl / 3, kx = tl % 3;
#pragma unroll
        for (int m = 0; m < 4; ++m) {
            int arow = 2 * wv + (m >> 1) + ky;      // LDS row 0..17
            int apx  = ((m & 1) << 4) + l15 + kx;   // 0..33
            int R = b * PADW + y0 + arow;           // global padded row
            int slot = ((q << 2) + quad) ^ ((2 * R + apx) & 7);
            dst[m] = *(const bf16x8*)(smem + arow * ROWB + apx * 128 +
                                      slot * 16);
        }
    };
    auto ldB = [&](int tl, int q, bf16x8 (&dst)[4]) {
#pragma unroll
        for (int n = 0; n < 4; ++n) {
            int o = (n << 4) + l15;                 // storage col
            int slot = ((q << 2) + quad) ^ (l15 & 7);
            dst[n] = *(const bf16x8*)(smemB + tl * TAPB + o * 128 +
                                      slot * 16);
        }
    };
    auto init_p = [&](floatx4 (&acc)[4][4], const __hip_bfloat16* p) {
#pragma unroll
        for (int c = 0; c < 8; ++c) {
            alignas(16) __hip_bfloat16 hv[8];
            *(uint4*)hv = *(const uint4*)((const char*)p + pbase + c * 16);
#pragma unroll
            for (int k = 0; k < 8; ++k) {
                int j = c * 8 + k;
                acc[j >> 4][(j >> 2) & 3][j & 3] = __bfloat162float(hv[k]);
            }
        }
    };
    auto epi_p = [&](floatx4 (&acc)[4][4], __hip_bfloat16* p) {
#pragma unroll
        for (int c = 0; c < 8; ++c) {
            alignas(16) __hip_bfloat16 hv[8];
#pragma unroll
            for (int k = 0; k < 8; ++k) {
                int j = c * 8 + k;
                hv[k] = __float2bfloat16(acc[j >> 4][(j >> 2) & 3][j & 3]);
            }
            *(uint4*)((char*)p + pbase + c * 16) = *(const uint4*)hv;
        }
    };
    auto epi_node = [&](floatx4 (&acc)[4][4], __hip_bfloat16* dst) {
#pragma unroll
        for (int m = 0; m < 4; ++m) {
            int row = y0 + 2 * wv + (m >> 1);
#pragma unroll
            for (int r = 0; r < 4; ++r) {
                int x = ((m & 1) << 4) + (quad << 2) + r;
                int p = (b * PADW + row + 1) * PADW + x + 1;
                alignas(8) __hip_bfloat16 hv[4];
#pragma unroll
                for (int n = 0; n < 4; ++n)
                    hv[n] = __float2bfloat16(fmaxf(acc[m][n][r], 0.f));
                char* d8 = (char*)dst + (size_t)p * 128 +
                           ((((l15 >> 1) ^ (p & 7)) << 4) + ((l15 & 1) << 3));
                *(uint2*)d8 = *(const uint2*)hv;
            }
        }
    };
    // shared-A paired pass: E_lds from smemB -> accL; E_reg from wtR[lR]
    // -> accR (B in regs, single-buffered per tap; verified R13b path).
    auto paired_pass = [&](int lR, floatx4 (&accL)[4][4],
                           floatx4 (&accR)[4][4]) {
        const char* gR = (const char*)wtR + (size_t)lR * 9 * TAPB;
#pragma unroll
        for (int t = 0; t < 9; ++t) {
            u32x4 Bb[8];
#pragma unroll
            for (int f = 0; f < 8; ++f)
                Bb[f] = *(const __attribute__((address_space(1))) u32x4*)
                    (gR + (size_t)t * TAPB + (f << 10) + (lane << 4));
#pragma unroll
            for (int q = 0; q < 2; ++q) {
                bf16x8 Af[4], Bf[4];
                ldA(t, q, Af);
                ldB(t, q, Bf);
                __builtin_amdgcn_s_setprio(1);
#pragma unroll
                for (int m = 0; m < 4; ++m)
#pragma unroll
                    for (int n = 0; n < 4; ++n)
                        accL[m][n] = __builtin_amdgcn_mfma_f32_16x16x32_bf16(
                            Af[m], Bf[n], accL[m][n], 0, 0, 0);
#pragma unroll
                for (int n = 0; n < 4; ++n) {
                    bf16x8 Br = __builtin_bit_cast(bf16x8, Bb[(q << 2) + n]);
#pragma unroll
                    for (int m = 0; m < 4; ++m)
                        accR[m][n] = __builtin_amdgcn_mfma_f32_16x16x32_bf16(
                            Af[m], Br, accR[m][n], 0, 0, 0);
                }
                __builtin_amdgcn_s_setprio(0);
            }
        }
    };
    // single-edge pass with R12's verified 1-deep fragment pipeline.
    auto single_pass = [&](floatx4 (&acc)[4][4]) {
        bf16x8 fA[2][4], fB[2][4];
        ldA(0, 0, fA[0]);
        ldB(0, 0, fB[0]);
#pragma unroll
        for (int st = 0; st < 18; ++st) {
            const int pb = st & 1;
            if (st < 17) {
                const int nt = (st + 1) >> 1, nq = (st + 1) & 1;
                ldA(nt, nq, fA[pb ^ 1]);
                ldB(nt, nq, fB[pb ^ 1]);
            }
            __builtin_amdgcn_s_setprio(1);
#pragma unroll
            for (int m = 0; m < 4; ++m)
#pragma unroll
                for (int n = 0; n < 4; ++n)
                    acc[m][n] = __builtin_amdgcn_mfma_f32_16x16x32_bf16(
                        fA[pb][m], fB[pb][n], acc[m][n], 0, 0, 0);
            __builtin_amdgcn_s_setprio(0);
        }
    };

    if constexpr (MODE == 1) {
        stage_A();
        stage_B(0);                  // E0 LDS-B
        floatx4 aT[4][4], aX[4][4];
        ZERO4(aT); ZERO4(aX);
        __syncthreads();             // A + B(E0) resident
        paired_pass(1, aT, aX);      // E0 -> aT, E1 -> aX (shared A)
        epi_node(aT, nodeOut);       // node1 = relu -> r1
        epi_p(aX, p2);               // p2 partial
        __syncthreads();             // waves done with B(E0) LDS
        stage_B(3);                  // E3 LDS-B (A untouched)
        __syncthreads();
        floatx4 aY[4][4];
        ZERO4(aY);
        single_pass(aY);             // E3 -> aY
        epi_p(aY, p3);               // p3 partial
    } else if constexpr (MODE == 2) {
        stage_A();
        stage_B(2);                  // E2 LDS-B
        floatx4 aX[4][4], aY[4][4];
        init_p(aX, p2);              // acc init overlaps staging wait
        init_p(aY, p3);
        __syncthreads();
        paired_pass(4, aX, aY);      // E2 -> aX, E4 -> aY (shared A)
        epi_node(aX, nodeOut);       // node2 = relu -> r2
        epi_p(aY, p3);               // p3 updated in place (thread-owned)
    } else {
        stage_A();
        stage_B(5);                  // E5 LDS-B
        floatx4 aY[4][4];
        init_p(aY, p3);
        __syncthreads();
        single_pass(aY);             // E5 -> aY
        // fp32 NCHW epilogue (oc = l15*4+n, verified R11/R12)
#pragma unroll
        for (int m = 0; m < 4; ++m) {
            int row = y0 + 2 * wv + (m >> 1);
#pragma unroll
            for (int n = 0; n < 4; ++n) {
                int o = (l15 << 2) + n;
                *(floatx4*)(finalOut +
                            (((size_t)b * 64 + o) * 32 + row) * 32 +
                            ((m & 1) << 4) + (quad << 2)) = aY[m][n];
            }
        }
    }
}

// ---------------------------------------------------------------------------
extern "C" void kernel_launch(void* const* d_in, const int* in_sizes, int n_in,
                              void* d_out, int out_size, void* d_ws,
                              size_t ws_size, hipStream_t stream) {
    const float* inputs  = (const float*)d_in[0];
    const float* alphas1 = (const float*)d_in[1];
    const float* alphas2 = (const float*)d_in[2];
    const float* W       = (const float*)d_in[3];
    char* ws = (char*)d_ws;

    __hip_bfloat16* wt  = (__hip_bfloat16*)(ws);                     // 432 KB
    __hip_bfloat16* wtR = (__hip_bfloat16*)(ws + ((size_t)1 << 19)); // 432 KB
    __hip_bfloat16* r0 = (__hip_bfloat16*)(ws + ((size_t)1 << 20));  // 18.9MB
    __hip_bfloat16* r1 = (__hip_bfloat16*)(ws + ((size_t)20 << 20));
    __hip_bfloat16* r2 = (__hip_bfloat16*)(ws + ((size_t)40 << 20));
    __hip_bfloat16* p2 = (__hip_bfloat16*)(ws + ((size_t)60 << 20)); // 16.8MB
    __hip_bfloat16* p3 = (__hip_bfloat16*)(ws + ((size_t)80 << 20)); // 16.8MB
    float* out = (float*)d_out;

    (void)hipFuncSetAttribute((const void*)conv_k<1>,
                              hipFuncAttributeMaxDynamicSharedMemorySize,
                              SMEM_BYTES);
    (void)hipFuncSetAttribute((const void*)conv_k<2>,
                              hipFuncAttributeMaxDynamicSharedMemorySize,
                              SMEM_BYTES);
    (void)hipFuncSetAttribute((const void*)conv_k<3>,
                              hipFuncAttributeMaxDynamicSharedMemorySize,
                              SMEM_BYTES);

    pre_kernel<<<864 + 128 + 4096, 256, 0, stream>>>(
        inputs, alphas1, alphas2, W, wt, wtR, r0, r1, r2);
    conv_k<1><<<256, 512, SMEM_BYTES, stream>>>(r0, wt, wtR, r1, nullptr,
                                                p2, p3);
    conv_k<2><<<256, 512, SMEM_BYTES, stream>>>(r1, wt, wtR, r2, nullptr,
                                                p2, p3);
    conv_k<3><<<256, 512, SMEM_BYTES, stream>>>(r2, wt, wtR, nullptr, out,
                                                p2, p3);
}